// Round 12
// baseline (270.876 us; speedup 1.0000x reference)
//
#include <hip/hip_runtime.h>

#define D_DIM 256
#define K_CODES 1024
#define HW 4096                  // H*W
#define BDHW 33554432            // 32*256*64*64
#define N_POS 131072             // 32*64*64
#define TAU 0.25f                // ~11 sigma of f16 pair-error

typedef __attribute__((ext_vector_type(8))) _Float16 half8v;
typedef __attribute__((ext_vector_type(4))) float float4v;

__device__ __forceinline__ void load_lds16(const void* g, void* l) {
    __builtin_amdgcn_global_load_lds(
        (const __attribute__((address_space(1))) unsigned int*)g,
        (__attribute__((address_space(3))) unsigned int*)l, 16, 0, 0);
}

// ---------------------------------------------------------------------------
// Kernel 1 (fused): pre-swizzled f16 embT chunks + enorm + count=0.
// ---------------------------------------------------------------------------
__global__ void vq_prep(const float* __restrict__ embed, uint4* __restrict__ embT,
                        float* __restrict__ enorm, int* __restrict__ count) {
    __shared__ float part[256];
    const int c  = blockIdx.x;                   // 64 chunks
    const int nc = c >> 3, dc = c & 7;
    const int t  = threadIdx.x;
#pragma unroll
    for (int i = 0; i < 2; ++i) {
        int p  = i * 256 + t;                    // piece 0..511 (16B each)
        int r  = p >> 2, sp = p & 3;
        int s  = sp ^ ((r >> 1) & 3);
        int k  = nc * 128 + r;
        int db = dc * 32 + s * 8;
        union { _Float16 h[8]; uint4 u; } pk;
#pragma unroll
        for (int j = 0; j < 8; ++j)
            pk.h[j] = (_Float16)embed[(size_t)(db + j) * K_CODES + k];
        embT[c * 512 + p] = pk.u;
    }
    if (dc == 0) {
        const int k = nc * 128 + (t & 127);
        const int hf = t >> 7;
        float s = 0.f;
#pragma unroll 4
        for (int d = hf * 128; d < hf * 128 + 128; ++d) {
            float e = embed[(size_t)d * K_CODES + k];
            s = fmaf(e, e, s);
        }
        part[t] = s;
        __syncthreads();
        if (t < 128) enorm[k] = part[t] + part[t + 128];
        if (c == 0 && t == 0) *count = 0;
    }
}

// ---------------------------------------------------------------------------
// Kernel 2: f16 MFMA distances + argmin. Round-6 schedule (ring-4 8KB,
// stage-ahead-2, vmcnt(4/2/0), 1 barrier/step) with HALVED tile: 64 pos/block
// (one (b,h) row), wave tile 32 pos x 64 codes. LDS 53248 B -> 3 blocks/CU
// (12 waves/CU, +50% occupancy vs the 69632-B 128-pos version).
// ---------------------------------------------------------------------------
__launch_bounds__(256, 3)
__global__ void vq_argmin(const float* __restrict__ input,
                          const char* __restrict__ embT,
                          const float* __restrict__ enorm,
                          float* __restrict__ indf,
                          int* __restrict__ count,
                          int* __restrict__ list) {
    __shared__ __align__(16) char lds[53248];
    char*  Als = lds;                            // 16 KB: row r<64 -> 256B, 16 slots, d=128+slot*8+j
    char*  Bls = lds + 16384;                    // 4 x 8 KB B ring
    float* Els = (float*)(lds + 49152);          // 4 KB enorm

    const int t    = threadIdx.x;
    const int lane = t & 63;
    const int wid  = t >> 6;
    const int blk  = blockIdx.x;                 // 2048 blocks
    const int n0   = blk * 64;
    const int b    = blk >> 6;
    const int h0   = blk & 63;
    const int wm = wid >> 1, wn = wid & 1;
    const int l15 = lane & 15, l4 = lane >> 4;

    const char* embTw = embT + wid * 2048 + lane * 16;   // per-wave stage base

    // ---- prologue: stage chunks 0,1 into ring slots 0,1
    load_lds16(embTw,                   Bls + wid * 2048);
    load_lds16(embTw + 1024,            Bls + wid * 2048 + 1024);
    load_lds16(embTw + 8192,            Bls + 8192 + wid * 2048);
    load_lds16(embTw + 8192 + 1024,     Bls + 8192 + wid * 2048 + 1024);

    // ---- stage enorm to LDS
    *reinterpret_cast<float4*>(Els + t * 4) =
        *reinterpret_cast<const float4*>(enorm + t * 4);

    // ---- stage A d in [128,256) to LDS (coalesced dword loads, b128 writes)
    const float* xbase = input + (size_t)b * (D_DIM * HW) + h0 * 64;
    {
        const int r  = lane;                      // pos = w
        const float* hp = xbase + lane;
        const int r7 = lane & 7;
#pragma unroll
        for (int q = 0; q < 4; ++q) {
            const int slot = wid * 4 + q;         // 0..15
            const int d = 128 + slot * 8;
            float v[8];
#pragma unroll
            for (int j = 0; j < 8; ++j) v[j] = hp[(size_t)(d + j) * HW];
            union { _Float16 h[8]; uint4 u; } pk;
#pragma unroll
            for (int j = 0; j < 8; ++j) pk.h[j] = (_Float16)v[j];
            const int byte = r * 256 + (((slot & 8) | ((slot & 7) ^ r7)) << 4);
            *reinterpret_cast<uint4*>(Als + byte) = pk.u;
        }
    }

    // ---- A d<128 directly global -> registers (this wave's 32 pos)
    half8v aR[2][4];                             // [mi][dcq], d = dcq*32 + l4*8 + j
    {
        const float* xw = xbase + wm * 32;
#pragma unroll
        for (int dcq = 0; dcq < 4; ++dcq)
#pragma unroll
            for (int mi = 0; mi < 2; ++mi) {
                const float* p = xw + (size_t)(dcq * 32 + l4 * 8) * HW + mi * 16 + l15;
                float v[8];
#pragma unroll
                for (int j = 0; j < 8; ++j) v[j] = p[(size_t)j * HW];
                union { _Float16 h[8]; half8v hv; } pk;
#pragma unroll
                for (int j = 0; j < 8; ++j) pk.h[j] = (_Float16)v[j];
                aR[mi][dcq] = pk.hv;
            }
    }

    asm volatile("s_waitcnt vmcnt(0) lgkmcnt(0)" ::: "memory");
    __builtin_amdgcn_s_barrier();
    __builtin_amdgcn_sched_barrier(0);

    // fragment base addresses
    const int r7a = l15 & 7;
    const int A0 = (wm * 32 + l15) * 256;                      // + mi*4096 + swz
    const int B0 = wn * 4096 + l15 * 64 + ((l4 ^ ((l15 >> 1) & 3)) << 4); // + ni*1024

    float m1[2][4], m2[2][4];
    int   i1[2][4];
#pragma unroll
    for (int mi = 0; mi < 2; ++mi)
#pragma unroll
        for (int r = 0; r < 4; ++r) { m1[mi][r] = 3.402823466e38f; m2[mi][r] = 3.402823466e38f; i1[mi][r] = 0; }

    float4v acc[2][4];

    for (int ss = 0; ss < 8; ++ss) {             // 8 nc chunks of 128 codes
#pragma unroll
        for (int dc = 0; dc < 8; ++dc) {         // K=32 steps (compile-time dc)
            const int s = ss * 8 + dc;
            // 1. stage chunk s+2 into ring slot (dc+2)&3
            if (ss < 7 || dc < 6) {
                const char* src = embTw + (size_t)(s + 2) * 8192;
                char* dst = Bls + ((dc + 2) & 3) * 8192 + wid * 2048;
                load_lds16(src, dst);
                load_lds16(src + 1024, dst + 1024);
            }
            // 2. counted wait
            if (ss < 7 || dc < 6)  asm volatile("s_waitcnt vmcnt(4)" ::: "memory");
            else if (dc == 6)      asm volatile("s_waitcnt vmcnt(2)" ::: "memory");
            else                   asm volatile("s_waitcnt vmcnt(0)" ::: "memory");
            // 3. one barrier per step
            __builtin_amdgcn_s_barrier();
            __builtin_amdgcn_sched_barrier(0);
            // 4. zero acc at chunk start
            if (dc == 0) {
#pragma unroll
                for (int mi = 0; mi < 2; ++mi)
#pragma unroll
                    for (int ni = 0; ni < 4; ++ni) acc[mi][ni] = (float4v){0.f, 0.f, 0.f, 0.f};
            }
            // 5. fragments
            const char* curB = Bls + (dc & 3) * 8192;
            half8v bF[4], aU[2];
#pragma unroll
            for (int ni = 0; ni < 4; ++ni)
                bF[ni] = *reinterpret_cast<const half8v*>(curB + B0 + ni * 1024);
            if (dc < 4) {
#pragma unroll
                for (int mi = 0; mi < 2; ++mi) aU[mi] = aR[mi][dc];
            } else {
                const int slot = (dc - 4) * 4 + l4;
                const int swz = ((slot & 8) | ((slot & 7) ^ r7a)) << 4;
#pragma unroll
                for (int mi = 0; mi < 2; ++mi)
                    aU[mi] = *reinterpret_cast<const half8v*>(Als + A0 + mi * 4096 + swz);
            }
            // 6. MFMA (8 per step)
            __builtin_amdgcn_s_setprio(1);
#pragma unroll
            for (int mi = 0; mi < 2; ++mi)
#pragma unroll
                for (int ni = 0; ni < 4; ++ni)
                    acc[mi][ni] = __builtin_amdgcn_mfma_f32_16x16x32_f16(aU[mi], bF[ni], acc[mi][ni], 0, 0, 0);
            __builtin_amdgcn_s_setprio(0);
            // 7. epilogue per 128-code chunk
            if (dc == 7) {
#pragma unroll
                for (int ni = 0; ni < 4; ++ni) {
                    int code = ss * 128 + wn * 64 + ni * 16 + l15;
                    float en = Els[code];
#pragma unroll
                    for (int mi = 0; mi < 2; ++mi)
#pragma unroll
                        for (int r = 0; r < 4; ++r) {
                            float sv = fmaf(-2.f, acc[mi][ni][r], en);
                            if (sv < m1[mi][r]) { m2[mi][r] = m1[mi][r]; m1[mi][r] = sv; i1[mi][r] = code; }
                            else m2[mi][r] = fminf(m2[mi][r], sv);
                        }
                }
            }
        }
    }

    // butterfly across the 16 column-lanes (lex-min on (val, idx), keep min2)
#pragma unroll
    for (int mi = 0; mi < 2; ++mi)
#pragma unroll
        for (int r = 0; r < 4; ++r) {
            float a1 = m1[mi][r], a2 = m2[mi][r]; int ai = i1[mi][r];
#pragma unroll
            for (int m = 8; m >= 1; m >>= 1) {
                float b1 = __shfl_xor(a1, m, 64);
                float b2 = __shfl_xor(a2, m, 64);
                int   bi = __shfl_xor(ai, m, 64);
                bool take = (b1 < a1) || (b1 == a1 && bi < ai);
                float hi = take ? a1 : b1;
                a1 = take ? b1 : a1;
                ai = take ? bi : ai;
                a2 = fminf(fminf(a2, b2), hi);
            }
            m1[mi][r] = a1; m2[mi][r] = a2; i1[mi][r] = ai;
        }

    __syncthreads();                             // done with A/B/enorm; reuse LDS
    float* Lm1 = reinterpret_cast<float*>(lds);  // [2][64]
    float* Lm2 = Lm1 + 128;
    int*   Li1 = reinterpret_cast<int*>(Lm2 + 128);
    if (l15 == 0) {
#pragma unroll
        for (int mi = 0; mi < 2; ++mi)
#pragma unroll
            for (int r = 0; r < 4; ++r) {
                int pos = wm * 32 + mi * 16 + l4 * 4 + r;
                Lm1[wn * 64 + pos] = m1[mi][r];
                Lm2[wn * 64 + pos] = m2[mi][r];
                Li1[wn * 64 + pos] = i1[mi][r];
            }
    }
    __syncthreads();
    if (t < 64) {
        float a1 = Lm1[t], a2 = Lm2[t]; int ai = Li1[t];
        float b1 = Lm1[64 + t], b2 = Lm2[64 + t]; int bi = Li1[64 + t];
        bool take = (b1 < a1) || (b1 == a1 && bi < ai);
        float hi = take ? a1 : b1;
        float f1 = take ? b1 : a1;
        int   fi = take ? bi : ai;
        float f2 = fminf(fminf(a2, b2), hi);
        int n = n0 + t;
        indf[n] = (float)fi;
        if (f2 - f1 < TAU) {                     // near-tie: exact rescan later
            int slot = atomicAdd(count, 1);
            list[slot] = n;
        }
    }
}

// ---------------------------------------------------------------------------
// Kernel 3: exact fp32 rescan — 8 positions per 128-thr block, K split
// across the 2 waves, LDS combine (round-11 version, passed).
// ---------------------------------------------------------------------------
__launch_bounds__(128, 4)
__global__ void vq_refine(const float* __restrict__ input,
                          const float* __restrict__ embed,
                          const float* __restrict__ enorm,
                          float* __restrict__ indf,
                          const int* __restrict__ count,
                          const int* __restrict__ list) {
    __shared__ float xls[8][D_DIM];
    __shared__ float sLs[2][8];
    __shared__ int   sLk[2][8];
    const int t    = threadIdx.x;                // 0..127
    const int wv   = t >> 6;
    const int lane = t & 63;
    const int cnt  = *count;
    if (cnt == 0) return;
    const int ngroups = (cnt + 7) >> 3;

    const int k0 = wv * 512 + lane * 8;          // this lane's 8 codes
    const float* ep = embed + k0;
    float en[8];
    {
        float4 e0 = *reinterpret_cast<const float4*>(enorm + k0);
        float4 e1 = *reinterpret_cast<const float4*>(enorm + k0 + 4);
        en[0]=e0.x; en[1]=e0.y; en[2]=e0.z; en[3]=e0.w;
        en[4]=e1.x; en[5]=e1.y; en[6]=e1.z; en[7]=e1.w;
    }

    for (int g = blockIdx.x; g < ngroups; g += gridDim.x) {
        __syncthreads();                         // xls/sL reuse safe
#pragma unroll
        for (int j = 0; j < 16; ++j) {
            const int p = j >> 1;
            const int d = (j & 1) * 128 + t;
            int li = g * 8 + p; if (li >= cnt) li = cnt - 1;   // tail dup: benign
            const int n = list[li];
            const int b = n >> 12, rem = n & 4095;
            xls[p][d] = input[(size_t)b * (D_DIM * HW) + (size_t)d * HW + rem];
        }
        __syncthreads();

        float acc[8][8];
#pragma unroll
        for (int p = 0; p < 8; ++p)
#pragma unroll
            for (int j = 0; j < 8; ++j) acc[p][j] = 0.f;

        for (int d = 0; d < D_DIM; ++d) {
            const float* er = ep + (size_t)d * K_CODES;
            float4 e0 = *reinterpret_cast<const float4*>(er);
            float4 e1 = *reinterpret_cast<const float4*>(er + 4);
            float ea[8] = {e0.x, e0.y, e0.z, e0.w, e1.x, e1.y, e1.z, e1.w};
#pragma unroll
            for (int p = 0; p < 8; ++p) {
                float xd = xls[p][d];
#pragma unroll
                for (int j = 0; j < 8; ++j)
                    acc[p][j] = fmaf(xd, ea[j], acc[p][j]);
            }
        }

#pragma unroll
        for (int p = 0; p < 8; ++p) {
            float bs = 3.402823466e38f; int bk = 0;
#pragma unroll
            for (int j = 0; j < 8; ++j) {
                float s = fmaf(-2.f, acc[p][j], en[j]);
                if (s < bs) { bs = s; bk = k0 + j; }
            }
#pragma unroll
            for (int m = 32; m >= 1; m >>= 1) {
                float os = __shfl_xor(bs, m, 64);
                int   ok = __shfl_xor(bk, m, 64);
                if (os < bs || (os == bs && ok < bk)) { bs = os; bk = ok; }
            }
            if (lane == 0) { sLs[wv][p] = bs; sLk[wv][p] = bk; }
        }
        __syncthreads();
        if (t < 8) {
            float a = sLs[0][t]; int ak = sLk[0][t];
            float c = sLs[1][t]; int ck = sLk[1][t];
            bool take = (c < a) || (c == a && ck < ak);
            int li = g * 8 + t; if (li >= cnt) li = cnt - 1;
            indf[list[li]] = (float)(take ? ck : ak);
        }
    }
}

// ---------------------------------------------------------------------------
// Kernel 4: gather outputs (overwrites the scratch regions last)
// ---------------------------------------------------------------------------
__global__ void vq_gather(const float* __restrict__ embed,
                          const float* __restrict__ indf,
                          float* __restrict__ out0,
                          float* __restrict__ out1) {
    int gid = blockIdx.x * 256 + threadIdx.x;    // BDHW/4 threads
    int w4   = (gid & 15) * 4;
    int rest = gid >> 4;
    int h  = rest & 63;
    int bd = rest >> 6;
    int d  = bd & 255;
    int b  = bd >> 8;
    int n  = (b * 64 + h) * 64 + w4;
    float4 fi = *reinterpret_cast<const float4*>(indf + n);
    const float* erow = embed + (size_t)d * K_CODES;
    float4 q;
    q.x = erow[(int)fi.x];
    q.y = erow[(int)fi.y];
    q.z = erow[(int)fi.z];
    q.w = erow[(int)fi.w];
    size_t o = (size_t)gid * 4;
    *reinterpret_cast<float4*>(out0 + o) = q;
    *reinterpret_cast<float4*>(out1 + o) = q;
}

// ---------------------------------------------------------------------------
extern "C" void kernel_launch(void* const* d_in, const int* in_sizes, int n_in,
                              void* d_out, int out_size, void* d_ws, size_t ws_size,
                              hipStream_t stream) {
    const float* input = (const float*)d_in[0];  // [32, 256, 64, 64] f32
    const float* embed = (const float*)d_in[1];  // [256, 1024] f32
    float* out0 = (float*)d_out;
    float* out1 = out0 + (size_t)BDHW;
    float* indf = out0 + (size_t)2 * BDHW;

    // scratch inside d_out (overwritten by vq_gather at the end):
    uint4* embT  = (uint4*)out0;                 // 512 KB pre-swizzled f16 chunks
    float* enorm = out0 + 131072;                // 4 KB (right after embT)
    int* count = (int*)out1;
    int* list  = (int*)out1 + 1;

    vq_prep  <<<64,         256, 0, stream>>>(embed, embT, enorm, count);
    vq_argmin<<<N_POS / 64, 256, 0, stream>>>(input, (const char*)embT, enorm, indf, count, list);
    vq_refine<<<512,        128, 0, stream>>>(input, embed, enorm, indf, count, list);
    vq_gather<<<BDHW / 1024, 256, 0, stream>>>(embed, indf, out0, out1);
}